// Round 1
// baseline (182.622 us; speedup 1.0000x reference)
//
#include <hip/hip_runtime.h>
#include <cstdint>

typedef __attribute__((ext_vector_type(8))) short short8;      // 8 bf16 = 4 VGPRs
typedef __attribute__((ext_vector_type(4))) float floatx4;     // MFMA C/D frag
typedef __attribute__((ext_vector_type(4))) _Float16 half4;    // 16x16x16 f16 A/B frag

#define DEV __device__ __forceinline__

constexpr int NB = 2, Lseq = 2048, NH = 16, HD = 64, EMB = 1024;
// fold softmax scale (1/sqrt(1024)) and log2(e) into Wq so flash uses exp2
constexpr float QSCALE = 0.03125f * 1.4426950408889634f;

DEV uint16_t f2bf(float f) {  // round-to-nearest-even f32 -> bf16
  uint32_t x = __builtin_bit_cast(uint32_t, f);
  x += 0x7fffu + ((x >> 16) & 1u);
  return (uint16_t)(x >> 16);
}

// pack two f32 -> two bf16 in one dword (round-half-up via bias, then v_perm)
DEV uint32_t pack2(float lo, float hi) {
  uint32_t a = __builtin_bit_cast(uint32_t, lo) + 0x8000u;
  uint32_t b = __builtin_bit_cast(uint32_t, hi) + 0x8000u;
  return __builtin_amdgcn_perm(b, a, 0x07060302);
}

DEV uint32_t packh2(float lo, float hi) {  // two f32 -> packed f16 dword
  return __builtin_bit_cast(uint32_t, __builtin_amdgcn_cvt_pkrtz(lo, hi));
}

DEV void gl_lds16(const void* g, void* l) {  // async global->LDS, 16B/lane
  __builtin_amdgcn_global_load_lds((const __attribute__((address_space(1))) void*)g,
                                   (__attribute__((address_space(3))) void*)l, 16, 0, 0);
}

// load 8 consecutive f32, scale, convert to a bf16 MFMA frag chunk
DEV short8 ld8bf(const float* p, float sc) {
  float4 u = *(const float4*)p;
  float4 v = *(const float4*)(p + 4);
  union { short8 s; uint32_t d[4]; } r;
  r.d[0] = pack2(u.x * sc, u.y * sc);
  r.d[1] = pack2(u.z * sc, u.w * sc);
  r.d[2] = pack2(v.x * sc, v.y * sc);
  r.d[3] = pack2(v.z * sc, v.w * sc);
  return r.s;
}

// ---------------- prep: Q/K/V projections (MFMA, LDS-free) + Wout cvt ----------------
__global__ __launch_bounds__(256) void prep_kernel(
    const float* __restrict__ values, const float* __restrict__ keysrc,
    const float* __restrict__ query, const float* __restrict__ Wv,
    const float* __restrict__ Wk, const float* __restrict__ Wq,
    const float* __restrict__ Wout,
    uint16_t* __restrict__ qp, uint16_t* __restrict__ kp,
    uint16_t* __restrict__ vp, uint16_t* __restrict__ wbf) {
  const int t = threadIdx.x, w = t >> 6, lane = t & 63;
  const int quad = lane >> 4, l16 = lane & 15;
  const int wid = blockIdx.x * 4 + w;
  const int mat = wid >> 10, sub = wid & 1023;

  if (mat == 3) {  // Wout f32 -> bf16
#pragma unroll
    for (int i = 0; i < 4; ++i) {
      int idx = sub * 256 + i * 64 + lane;
      float4 v = ((const float4*)Wout)[idx];
      uint2 p;
      p.x = pack2(v.x, v.y);
      p.y = pack2(v.z, v.w);
      ((uint2*)wbf)[idx] = p;
    }
    return;
  }

  floatx4 c[4][4];
#pragma unroll
  for (int i = 0; i < 4; ++i)
#pragma unroll
    for (int j = 0; j < 4; ++j) c[i][j] = floatx4{0.f, 0.f, 0.f, 0.f};

  if (mat < 2) {
    // Q/K: A = W rows (m=e), B = x rows (n=r) -> D[e][r]; lane holds 4 consecutive e.
    const float* src = mat ? keysrc : query;
    const float* W   = mat ? Wk : Wq;
    const float asc  = mat ? 1.f : QSCALE;
    uint16_t* dst    = mat ? kp : qp;
    const int R0 = sub * 64;
    short8 a[4][2], b[4][2];
#pragma unroll
    for (int dc = 0; dc < 2; ++dc) {
#pragma unroll
      for (int f = 0; f < 4; ++f) {
        a[f][dc] = ld8bf(W + (size_t)(f * 16 + l16) * 64 + dc * 32 + quad * 8, asc);
        b[f][dc] = ld8bf(src + (size_t)(R0 + f * 16 + l16) * 64 + dc * 32 + quad * 8, 1.f);
      }
    }
#pragma unroll
    for (int dc = 0; dc < 2; ++dc)
#pragma unroll
      for (int mf = 0; mf < 4; ++mf)
#pragma unroll
        for (int nf = 0; nf < 4; ++nf)
          c[mf][nf] = __builtin_amdgcn_mfma_f32_16x16x32_bf16(a[mf][dc], b[nf][dc], c[mf][nf], 0, 0, 0);
#pragma unroll
    for (int nf = 0; nf < 4; ++nf) {
      int r = R0 + nf * 16 + l16;
      int h = r & 15, l = (r >> 4) & 2047, n = r >> 15;
      uint16_t* drow = dst + ((size_t)(n * 16 + h) * 2048 + l) * 64;
#pragma unroll
      for (int mf = 0; mf < 4; ++mf) {
        uint2 pk;
        pk.x = pack2(c[mf][nf][0], c[mf][nf][1]);
        pk.y = pack2(c[mf][nf][2], c[mf][nf][3]);
        *(uint2*)(drow + mf * 16 + quad * 4) = pk;
      }
    }
  } else {
    // V^T: A = x rows (m=l), B = Wv rows (n=d) -> D[l][d]; vp[nh][d][l] in f16.
    const int nh = sub >> 5, L0 = (sub & 31) * 64;
    const int n = nh >> 4, h = nh & 15;
    short8 a[4][2], b[4][2];
#pragma unroll
    for (int dc = 0; dc < 2; ++dc) {
#pragma unroll
      for (int f = 0; f < 4; ++f) {
        a[f][dc] = ld8bf(values + (size_t)(n * 2048 + L0 + f * 16 + l16) * 1024 + h * 64 + dc * 32 + quad * 8, 1.f);
        b[f][dc] = ld8bf(Wv + (size_t)(f * 16 + l16) * 64 + dc * 32 + quad * 8, 1.f);
      }
    }
#pragma unroll
    for (int dc = 0; dc < 2; ++dc)
#pragma unroll
      for (int mf = 0; mf < 4; ++mf)
#pragma unroll
        for (int nf = 0; nf < 4; ++nf)
          c[mf][nf] = __builtin_amdgcn_mfma_f32_16x16x32_bf16(a[mf][dc], b[nf][dc], c[mf][nf], 0, 0, 0);
#pragma unroll
    for (int nf = 0; nf < 4; ++nf) {
      int d = nf * 16 + l16;
      uint16_t* drow = vp + ((size_t)nh * 64 + d) * 2048 + L0;
#pragma unroll
      for (int mf = 0; mf < 4; ++mf) {
        uint2 pk;
        pk.x = packh2(c[mf][nf][0], c[mf][nf][1]);
        pk.y = packh2(c[mf][nf][2], c[mf][nf][3]);
        *(uint2*)(drow + mf * 16 + quad * 4) = pk;
      }
    }
  }
}

// ---------------- Flash attention: FULL key range, normalized bf16 X output --------
// kh split removed (kbn 16->32): 512 blocks = 2/CU resident, so the split bought no
// occupancy — only a 32MB f32 partial round-trip. Epilogue normalizes O by 1/l
// (ones-MFMA accumulator: every reg of lfr[qb] == l_q) and stores bf16 X[q][h*64+d].
// Grid (x=nh, y=qt): linear%8 = nh%8 -> all 16 qt sharers of one head's K/V on one
// XCD (K+V working set ~512KB/head, 4 heads/XCD fits 4MB L2).
__global__ __launch_bounds__(256, 4) void flash_kernel(const uint16_t* __restrict__ qp,
                                                       const uint16_t* __restrict__ kp,
                                                       const uint16_t* __restrict__ vp,
                                                       uint16_t* __restrict__ xg) {
  constexpr int kbn = 32;
  __shared__ uint16_t Kt[2][64 * 64];    // swizzled [key][d] bf16
  __shared__ uint16_t Vt[2][64 * 64];    // swizzled [d][key] f16
  const int t = threadIdx.x;
  const int w = t >> 6, lane = t & 63, quad = lane >> 4, l16 = lane & 15;
  const int nh = blockIdx.x, qt = blockIdx.y;
  const int q0 = qt * 128 + w * 32;
  const uint16_t* Qb = qp + (size_t)nh * Lseq * HD;
  const uint16_t* Kb = kp + (size_t)nh * Lseq * HD;
  const uint16_t* Vb = vp + (size_t)nh * HD * Lseq;
  const int srow = lane >> 3, sc8 = (lane & 7) ^ (lane >> 3);  // staging swizzle

  short8 bq[2][2];
#pragma unroll
  for (int qb = 0; qb < 2; ++qb) {
    bq[qb][0] = *(const short8*)(Qb + (q0 + qb * 16 + l16) * 64 + quad * 8);
    bq[qb][1] = *(const short8*)(Qb + (q0 + qb * 16 + l16) * 64 + 32 + quad * 8);
  }

  floatx4 o[4][2];   // O^T frags: row=d=quad*4+r, col=q=l16
  floatx4 lfr[2];    // ones^T P accumulator: every element = l_q for q=qb*16+l16
#pragma unroll
  for (int i = 0; i < 4; ++i)
#pragma unroll
    for (int qb = 0; qb < 2; ++qb) o[i][qb] = floatx4{0.f, 0.f, 0.f, 0.f};
  lfr[0] = lfr[1] = floatx4{0.f, 0.f, 0.f, 0.f};
  const _Float16 one = (_Float16)1.0f;
  const half4 vone = {one, one, one, one};

#pragma unroll
  for (int i = 0; i < 2; ++i) {
    int r0 = w * 16 + i * 8;
    gl_lds16(Kb + (r0 + srow) * 64 + sc8 * 8, &Kt[0][r0 * 64]);
    gl_lds16(Vb + (size_t)(r0 + srow) * Lseq + sc8 * 8, &Vt[0][r0 * 64]);
  }

  for (int kb = 0; kb < kbn; ++kb) {
    __syncthreads();
    const int cur = kb & 1;
    if (kb + 1 < kbn) {
      const int nxt = cur ^ 1;
      const uint16_t* kg = Kb + (kb + 1) * (64 * 64);
#pragma unroll
      for (int i = 0; i < 2; ++i) {
        int r0 = w * 16 + i * 8;
        gl_lds16(kg + (r0 + srow) * 64 + sc8 * 8, &Kt[nxt][r0 * 64]);
        gl_lds16(Vb + (size_t)(r0 + srow) * Lseq + (kb + 1) * 64 + sc8 * 8, &Vt[nxt][r0 * 64]);
      }
    }

    // S^T = K Q^T
    floatx4 s[4][2];
#pragma unroll
    for (int kb16 = 0; kb16 < 4; ++kb16)
#pragma unroll
      for (int qb = 0; qb < 2; ++qb) s[kb16][qb] = floatx4{0.f, 0.f, 0.f, 0.f};
#pragma unroll
    for (int dc = 0; dc < 2; ++dc) {
#pragma unroll
      for (int kb16 = 0; kb16 < 4; ++kb16) {
        int row = kb16 * 16 + l16;
        short8 ak = *(const short8*)(&Kt[cur][row * 64 + ((dc * 4 + quad) ^ (row & 7)) * 8]);
        s[kb16][0] = __builtin_amdgcn_mfma_f32_16x16x32_bf16(ak, bq[0][dc], s[kb16][0], 0, 0, 0);
        s[kb16][1] = __builtin_amdgcn_mfma_f32_16x16x32_bf16(ak, bq[1][dc], s[kb16][1], 0, 0, 0);
      }
    }

    // p = exp2(s), packed in-register as 16x16x16 B-frags; l via ones-MFMA
    half4 bp[4][2];
#pragma unroll
    for (int qb = 0; qb < 2; ++qb) {
#pragma unroll
      for (int kb16 = 0; kb16 < 4; ++kb16) {
        float p0 = __builtin_amdgcn_exp2f(s[kb16][qb][0]);
        float p1 = __builtin_amdgcn_exp2f(s[kb16][qb][1]);
        float p2 = __builtin_amdgcn_exp2f(s[kb16][qb][2]);
        float p3 = __builtin_amdgcn_exp2f(s[kb16][qb][3]);
        union { half4 h4; uint32_t d[2]; } u;
        u.d[0] = packh2(p0, p1);
        u.d[1] = packh2(p2, p3);
        bp[kb16][qb] = u.h4;
      }
    }
#pragma unroll
    for (int kb16 = 0; kb16 < 4; ++kb16) {
      lfr[0] = __builtin_amdgcn_mfma_f32_16x16x16f16(vone, bp[kb16][0], lfr[0], 0, 0, 0);
      lfr[1] = __builtin_amdgcn_mfma_f32_16x16x16f16(vone, bp[kb16][1], lfr[1], 0, 0, 0);
    }

    // O^T += V^T P
#pragma unroll
    for (int kb16 = 0; kb16 < 4; ++kb16) {
#pragma unroll
      for (int db = 0; db < 4; ++db) {
        int row = db * 16 + l16;
        int ch = (kb16 * 2 + (quad >> 1)) ^ (row & 7);
        half4 av = *(const half4*)(&Vt[cur][row * 64 + ch * 8 + (quad & 1) * 4]);
        o[db][0] = __builtin_amdgcn_mfma_f32_16x16x16f16(av, bp[kb16][0], o[db][0], 0, 0, 0);
        o[db][1] = __builtin_amdgcn_mfma_f32_16x16x16f16(av, bp[kb16][1], o[db][1], 0, 0, 0);
      }
    }
  }

  // epilogue: X[n*2048 + q][h*64 + d] = (O^T[d][q] / l_q) as bf16.
  // Lane holds d = db*16 + quad*4 + {0..3} for its fixed q = q0 + qb*16 + l16,
  // so each (db,qb) is one aligned 8B uint2 store.
  const int nn = nh >> 4, h = nh & 15;
  const float inv0 = __builtin_amdgcn_rcpf(lfr[0][0]);
  const float inv1 = __builtin_amdgcn_rcpf(lfr[1][0]);
#pragma unroll
  for (int qb = 0; qb < 2; ++qb) {
    const float inv = qb ? inv1 : inv0;
    uint16_t* xr = xg + ((size_t)(nn * 2048 + q0 + qb * 16 + l16)) * 1024 + h * 64 + quad * 4;
#pragma unroll
    for (int db = 0; db < 4; ++db) {
      uint2 pk;
      pk.x = pack2(o[db][qb][0] * inv, o[db][qb][1] * inv);
      pk.y = pack2(o[db][qb][2] * inv, o[db][qb][3] * inv);
      *(uint2*)(xr + db * 16) = pk;
    }
  }
}

// ---------------- out GEMM: out = X @ Wout^T + bias, 64x128 tiles -------------------
// Clean bf16 GEMM (no combine — flash already normalized). Both A=X rows and B=Wout
// rows stride along e: gl_lds16 dbuf staging with pre-swizzled source addresses.
// Grid (x=64 mblk, y=8 obk): linear%8 = mblk%8 -> all 8 obk sharers of an X slab on
// one XCD. LDS 48KB -> 3 blocks/CU cap, 512 blocks = 2/CU resident.
__global__ __launch_bounds__(256, 2) void out_gemm(const uint16_t* __restrict__ Xg,
                                                   const uint16_t* __restrict__ Wb,
                                                   const float* __restrict__ bias,
                                                   float* __restrict__ out) {
  __shared__ uint16_t Xt[2][64 * 64];
  __shared__ uint16_t Wt[2][128 * 64];
  const int t = threadIdx.x, w = t >> 6, lane = t & 63, quad = lane >> 4, l16 = lane & 15;
  const int m0 = blockIdx.x * 64, o0 = blockIdx.y * 128;
  const int srow = lane >> 3, sc8 = (lane & 7) ^ (lane >> 3);

  floatx4 acc[8];
#pragma unroll
  for (int j = 0; j < 8; ++j) acc[j] = floatx4{0.f, 0.f, 0.f, 0.f};

  auto stage = [&](int buf, int kt) {
#pragma unroll
    for (int i = 0; i < 2; ++i) {   // X: 16 rows/wave
      int r0 = w * 16 + i * 8;
      gl_lds16(Xg + (size_t)(m0 + r0 + srow) * 1024 + kt * 64 + sc8 * 8, &Xt[buf][r0 * 64]);
    }
#pragma unroll
    for (int i = 0; i < 4; ++i) {   // W: 32 rows/wave
      int r0 = w * 32 + i * 8;
      gl_lds16(Wb + (size_t)(o0 + r0 + srow) * 1024 + kt * 64 + sc8 * 8, &Wt[buf][r0 * 64]);
    }
  };

  stage(0, 0);

  for (int kt = 0; kt < 16; ++kt) {
    const int cur = kt & 1;
    __syncthreads();                 // drains cur-buffer DMA; prev-buffer reads done
    if (kt + 1 < 16) stage(cur ^ 1, kt + 1);
#pragma unroll
    for (int kc = 0; kc < 2; ++kc) {
      int ra = w * 16 + l16;
      short8 a = *(const short8*)(&Xt[cur][ra * 64 + ((kc * 4 + quad) ^ (ra & 7)) * 8]);
#pragma unroll
      for (int nf = 0; nf < 8; ++nf) {
        int rb = nf * 16 + l16;
        short8 b = *(const short8*)(&Wt[cur][rb * 64 + ((kc * 4 + quad) ^ (rb & 7)) * 8]);
        acc[nf] = __builtin_amdgcn_mfma_f32_16x16x32_bf16(a, b, acc[nf], 0, 0, 0);
      }
    }
  }

#pragma unroll
  for (int nf = 0; nf < 8; ++nf) {
    float bv = bias[o0 + nf * 16 + l16];
#pragma unroll
    for (int r = 0; r < 4; ++r)
      out[(size_t)(m0 + w * 16 + quad * 4 + r) * 1024 + o0 + nf * 16 + l16] = acc[nf][r] + bv;
  }
}

extern "C" void kernel_launch(void* const* d_in, const int* in_sizes, int n_in,
                              void* d_out, int out_size, void* d_ws, size_t ws_size,
                              hipStream_t stream) {
  const float* values = (const float*)d_in[0];
  const float* keys   = (const float*)d_in[1];
  const float* query  = (const float*)d_in[2];
  const float* Wv     = (const float*)d_in[3];
  const float* Wk     = (const float*)d_in[4];
  const float* Wq     = (const float*)d_in[5];
  const float* Wout   = (const float*)d_in[6];
  const float* bout   = (const float*)d_in[7];
  float* out = (float*)d_out;
  (void)ws_size;

  uint16_t* ws  = (uint16_t*)d_ws;
  uint16_t* qp  = ws;                                // 8 MB bf16 [nh][l][d]
  uint16_t* kp  = ws + (size_t)4194304;              // 8 MB bf16 [nh][l][d]
  uint16_t* vp  = ws + (size_t)8388608;              // 8 MB f16  [nh][d][l]
  uint16_t* wbf = ws + (size_t)12582912;             // 2 MB bf16 Wout
  uint16_t* xp  = ws + (size_t)13631488;             // 8 MB bf16 X = normalized attn out

  prep_kernel<<<dim3(1024), dim3(256), 0, stream>>>(values, keys, query, Wv, Wk, Wq, Wout,
                                                    qp, kp, vp, wbf);
  flash_kernel<<<dim3(32, 16), dim3(256), 0, stream>>>(qp, kp, vp, xp);
  out_gemm<<<dim3(64, 8), dim3(256), 0, stream>>>(xp, wbf, bout, out);
}

// Round 2
// 180.783 us; speedup vs baseline: 1.0102x; 1.0102x over previous
//
#include <hip/hip_runtime.h>
#include <cstdint>

typedef __attribute__((ext_vector_type(8))) short short8;      // 8 bf16 = 4 VGPRs
typedef __attribute__((ext_vector_type(4))) float floatx4;     // MFMA C/D frag
typedef __attribute__((ext_vector_type(4))) _Float16 half4;    // 16x16x16 f16 A/B frag

#define DEV __device__ __forceinline__

constexpr int NB = 2, Lseq = 2048, NH = 16, HD = 64, EMB = 1024;
// fold softmax scale (1/sqrt(1024)) and log2(e) into Wq so flash uses exp2
constexpr float QSCALE = 0.03125f * 1.4426950408889634f;

DEV uint16_t f2bf(float f) {  // round-to-nearest-even f32 -> bf16
  uint32_t x = __builtin_bit_cast(uint32_t, f);
  x += 0x7fffu + ((x >> 16) & 1u);
  return (uint16_t)(x >> 16);
}

// pack two f32 -> two bf16 in one dword (round-half-up via bias, then v_perm)
DEV uint32_t pack2(float lo, float hi) {
  uint32_t a = __builtin_bit_cast(uint32_t, lo) + 0x8000u;
  uint32_t b = __builtin_bit_cast(uint32_t, hi) + 0x8000u;
  return __builtin_amdgcn_perm(b, a, 0x07060302);
}

DEV uint32_t packh2(float lo, float hi) {  // two f32 -> packed f16 dword
  return __builtin_bit_cast(uint32_t, __builtin_amdgcn_cvt_pkrtz(lo, hi));
}

DEV void gl_lds16(const void* g, void* l) {  // async global->LDS, 16B/lane
  __builtin_amdgcn_global_load_lds((const __attribute__((address_space(1))) void*)g,
                                   (__attribute__((address_space(3))) void*)l, 16, 0, 0);
}

// load 8 consecutive f32, scale, convert to a bf16 MFMA frag chunk
DEV short8 ld8bf(const float* p, float sc) {
  float4 u = *(const float4*)p;
  float4 v = *(const float4*)(p + 4);
  union { short8 s; uint32_t d[4]; } r;
  r.d[0] = pack2(u.x * sc, u.y * sc);
  r.d[1] = pack2(u.z * sc, u.w * sc);
  r.d[2] = pack2(v.x * sc, v.y * sc);
  r.d[3] = pack2(v.z * sc, v.w * sc);
  return r.s;
}

// ---------------- prep: Q/K/V projections (MFMA, LDS-free) + Wout cvt ----------------
__global__ __launch_bounds__(256) void prep_kernel(
    const float* __restrict__ values, const float* __restrict__ keysrc,
    const float* __restrict__ query, const float* __restrict__ Wv,
    const float* __restrict__ Wk, const float* __restrict__ Wq,
    const float* __restrict__ Wout,
    uint16_t* __restrict__ qp, uint16_t* __restrict__ kp,
    uint16_t* __restrict__ vp, uint16_t* __restrict__ wbf) {
  const int t = threadIdx.x, w = t >> 6, lane = t & 63;
  const int quad = lane >> 4, l16 = lane & 15;
  const int wid = blockIdx.x * 4 + w;
  const int mat = wid >> 10, sub = wid & 1023;

  if (mat == 3) {  // Wout f32 -> bf16
#pragma unroll
    for (int i = 0; i < 4; ++i) {
      int idx = sub * 256 + i * 64 + lane;
      float4 v = ((const float4*)Wout)[idx];
      uint2 p;
      p.x = pack2(v.x, v.y);
      p.y = pack2(v.z, v.w);
      ((uint2*)wbf)[idx] = p;
    }
    return;
  }

  floatx4 c[4][4];
#pragma unroll
  for (int i = 0; i < 4; ++i)
#pragma unroll
    for (int j = 0; j < 4; ++j) c[i][j] = floatx4{0.f, 0.f, 0.f, 0.f};

  if (mat < 2) {
    // Q/K: A = W rows (m=e), B = x rows (n=r) -> D[e][r]; lane holds 4 consecutive e.
    const float* src = mat ? keysrc : query;
    const float* W   = mat ? Wk : Wq;
    const float asc  = mat ? 1.f : QSCALE;
    uint16_t* dst    = mat ? kp : qp;
    const int R0 = sub * 64;
    short8 a[4][2], b[4][2];
#pragma unroll
    for (int dc = 0; dc < 2; ++dc) {
#pragma unroll
      for (int f = 0; f < 4; ++f) {
        a[f][dc] = ld8bf(W + (size_t)(f * 16 + l16) * 64 + dc * 32 + quad * 8, asc);
        b[f][dc] = ld8bf(src + (size_t)(R0 + f * 16 + l16) * 64 + dc * 32 + quad * 8, 1.f);
      }
    }
#pragma unroll
    for (int dc = 0; dc < 2; ++dc)
#pragma unroll
      for (int mf = 0; mf < 4; ++mf)
#pragma unroll
        for (int nf = 0; nf < 4; ++nf)
          c[mf][nf] = __builtin_amdgcn_mfma_f32_16x16x32_bf16(a[mf][dc], b[nf][dc], c[mf][nf], 0, 0, 0);
#pragma unroll
    for (int nf = 0; nf < 4; ++nf) {
      int r = R0 + nf * 16 + l16;
      int h = r & 15, l = (r >> 4) & 2047, n = r >> 15;
      uint16_t* drow = dst + ((size_t)(n * 16 + h) * 2048 + l) * 64;
#pragma unroll
      for (int mf = 0; mf < 4; ++mf) {
        uint2 pk;
        pk.x = pack2(c[mf][nf][0], c[mf][nf][1]);
        pk.y = pack2(c[mf][nf][2], c[mf][nf][3]);
        *(uint2*)(drow + mf * 16 + quad * 4) = pk;
      }
    }
  } else {
    // V^T: A = x rows (m=l), B = Wv rows (n=d) -> D[l][d]; vp[nh][d][l] in f16.
    const int nh = sub >> 5, L0 = (sub & 31) * 64;
    const int n = nh >> 4, h = nh & 15;
    short8 a[4][2], b[4][2];
#pragma unroll
    for (int dc = 0; dc < 2; ++dc) {
#pragma unroll
      for (int f = 0; f < 4; ++f) {
        a[f][dc] = ld8bf(values + (size_t)(n * 2048 + L0 + f * 16 + l16) * 1024 + h * 64 + dc * 32 + quad * 8, 1.f);
        b[f][dc] = ld8bf(Wv + (size_t)(f * 16 + l16) * 64 + dc * 32 + quad * 8, 1.f);
      }
    }
#pragma unroll
    for (int dc = 0; dc < 2; ++dc)
#pragma unroll
      for (int mf = 0; mf < 4; ++mf)
#pragma unroll
        for (int nf = 0; nf < 4; ++nf)
          c[mf][nf] = __builtin_amdgcn_mfma_f32_16x16x32_bf16(a[mf][dc], b[nf][dc], c[mf][nf], 0, 0, 0);
#pragma unroll
    for (int nf = 0; nf < 4; ++nf) {
      int d = nf * 16 + l16;
      uint16_t* drow = vp + ((size_t)nh * 64 + d) * 2048 + L0;
#pragma unroll
      for (int mf = 0; mf < 4; ++mf) {
        uint2 pk;
        pk.x = packh2(c[mf][nf][0], c[mf][nf][1]);
        pk.y = packh2(c[mf][nf][2], c[mf][nf][3]);
        *(uint2*)(drow + mf * 16 + quad * 4) = pk;
      }
    }
  }
}

// ---------------- Flash attention: counted-vmcnt 3-buffer pipeline ------------------
// Full key range per block (512 blocks = 2/CU). The round-1 regression was the
// __syncthreads() vmcnt(0)-drain per 64-key tile exposed at 2 blocks/CU. Now:
// 3 LDS buffers, DMAs issued 2 tiles ahead, per-iter {vmcnt(4); s_barrier} keeps the
// newest tile's 4 loads in flight across the barrier (m218 counted-vmcnt pattern).
// lgkmcnt(0) before the barrier closes the WAR hazard on the recycled buffer.
// l is accumulated on the VALU from the f32 p-values (frees 8 ones-MFMA/iter) and
// reduced across quads with two shfl_xor at the end.
__global__ __launch_bounds__(256, 4) void flash_kernel(const uint16_t* __restrict__ qp,
                                                       const uint16_t* __restrict__ kp,
                                                       const uint16_t* __restrict__ vp,
                                                       uint16_t* __restrict__ xg) {
  constexpr int kbn = 32;
  __shared__ uint16_t Kt[3][64 * 64];    // swizzled [key][d] bf16
  __shared__ uint16_t Vt[3][64 * 64];    // swizzled [d][key] f16
  const int t = threadIdx.x;
  const int w = t >> 6, lane = t & 63, quad = lane >> 4, l16 = lane & 15;
  const int nh = blockIdx.x, qt = blockIdx.y;
  const int q0 = qt * 128 + w * 32;
  const uint16_t* Qb = qp + (size_t)nh * Lseq * HD;
  const uint16_t* Kb = kp + (size_t)nh * Lseq * HD;
  const uint16_t* Vb = vp + (size_t)nh * HD * Lseq;
  const int srow = lane >> 3, sc8 = (lane & 7) ^ (lane >> 3);  // staging swizzle

  // Q frags first: oldest vmem ops, so vmcnt(4) at iter 0 also covers them.
  short8 bq[2][2];
#pragma unroll
  for (int qb = 0; qb < 2; ++qb) {
    bq[qb][0] = *(const short8*)(Qb + (q0 + qb * 16 + l16) * 64 + quad * 8);
    bq[qb][1] = *(const short8*)(Qb + (q0 + qb * 16 + l16) * 64 + 32 + quad * 8);
  }

  floatx4 o[4][2];   // O^T frags: row=d=quad*4+r, col=q=l16
  float lsum[2] = {0.f, 0.f};  // per-lane partial of l_q (this quad's k-stripe)
#pragma unroll
  for (int i = 0; i < 4; ++i)
#pragma unroll
    for (int qb = 0; qb < 2; ++qb) o[i][qb] = floatx4{0.f, 0.f, 0.f, 0.f};

  auto issue = [&](int tile, int buf) {  // 4 DMA instrs/wave = one K+V 64-key tile
#pragma unroll
    for (int i = 0; i < 2; ++i) {
      int r0 = w * 16 + i * 8;
      gl_lds16(Kb + (size_t)tile * 4096 + (r0 + srow) * 64 + sc8 * 8, &Kt[buf][r0 * 64]);
      gl_lds16(Vb + (size_t)(r0 + srow) * Lseq + tile * 64 + sc8 * 8, &Vt[buf][r0 * 64]);
    }
  };

  issue(0, 0);
  issue(1, 1);

  int cur = 0;
  for (int kb = 0; kb < kbn; ++kb) {
    // tile kb landed (its 4 DMAs are oldest); tile kb+1's 4 stay in flight
    if (kb + 1 < kbn) asm volatile("s_waitcnt vmcnt(4)" ::: "memory");
    else              asm volatile("s_waitcnt vmcnt(0)" ::: "memory");
    __builtin_amdgcn_s_barrier();
    if (kb + 2 < kbn) {
      int tgt = cur + 2; if (tgt >= 3) tgt -= 3;
      issue(kb + 2, tgt);   // overwrites buffer of tile kb-1 (reads done pre-barrier)
    }

    // S^T = K Q^T
    floatx4 s[4][2];
#pragma unroll
    for (int kb16 = 0; kb16 < 4; ++kb16)
#pragma unroll
      for (int qb = 0; qb < 2; ++qb) s[kb16][qb] = floatx4{0.f, 0.f, 0.f, 0.f};
#pragma unroll
    for (int dc = 0; dc < 2; ++dc) {
#pragma unroll
      for (int kb16 = 0; kb16 < 4; ++kb16) {
        int row = kb16 * 16 + l16;
        short8 ak = *(const short8*)(&Kt[cur][row * 64 + ((dc * 4 + quad) ^ (row & 7)) * 8]);
        s[kb16][0] = __builtin_amdgcn_mfma_f32_16x16x32_bf16(ak, bq[0][dc], s[kb16][0], 0, 0, 0);
        s[kb16][1] = __builtin_amdgcn_mfma_f32_16x16x32_bf16(ak, bq[1][dc], s[kb16][1], 0, 0, 0);
      }
    }

    // p = exp2(s); accumulate l on VALU; pack P as 16x16x16 B-frags
    half4 bp[4][2];
#pragma unroll
    for (int qb = 0; qb < 2; ++qb) {
#pragma unroll
      for (int kb16 = 0; kb16 < 4; ++kb16) {
        float p0 = __builtin_amdgcn_exp2f(s[kb16][qb][0]);
        float p1 = __builtin_amdgcn_exp2f(s[kb16][qb][1]);
        float p2 = __builtin_amdgcn_exp2f(s[kb16][qb][2]);
        float p3 = __builtin_amdgcn_exp2f(s[kb16][qb][3]);
        lsum[qb] += (p0 + p1) + (p2 + p3);
        union { half4 h4; uint32_t d[2]; } u;
        u.d[0] = packh2(p0, p1);
        u.d[1] = packh2(p2, p3);
        bp[kb16][qb] = u.h4;
      }
    }

    // O^T += V^T P
#pragma unroll
    for (int kb16 = 0; kb16 < 4; ++kb16) {
#pragma unroll
      for (int db = 0; db < 4; ++db) {
        int row = db * 16 + l16;
        int ch = (kb16 * 2 + (quad >> 1)) ^ (row & 7);
        half4 av = *(const half4*)(&Vt[cur][row * 64 + ch * 8 + (quad & 1) * 4]);
        o[db][0] = __builtin_amdgcn_mfma_f32_16x16x16f16(av, bp[kb16][0], o[db][0], 0, 0, 0);
        o[db][1] = __builtin_amdgcn_mfma_f32_16x16x16f16(av, bp[kb16][1], o[db][1], 0, 0, 0);
      }
    }

    // all LDS reads of this tile complete before next barrier (WAR on recycled buf)
    asm volatile("s_waitcnt lgkmcnt(0)" ::: "memory");
    cur = (cur + 1 == 3) ? 0 : cur + 1;
  }

  // finish l: lane holds sum over its quad's k-stripe; reduce across quads
  // (lanes l16, l16+16, l16+32, l16+48 share the same q)
  float inv[2];
#pragma unroll
  for (int qb = 0; qb < 2; ++qb) {
    float v = lsum[qb];
    v += __shfl_xor(v, 16, 64);
    v += __shfl_xor(v, 32, 64);
    inv[qb] = __builtin_amdgcn_rcpf(v);
  }

  // epilogue: X[n*2048 + q][h*64 + d] = (O^T[d][q] / l_q) as bf16.
  const int nn = nh >> 4, h = nh & 15;
#pragma unroll
  for (int qb = 0; qb < 2; ++qb) {
    uint16_t* xr = xg + ((size_t)(nn * 2048 + q0 + qb * 16 + l16)) * 1024 + h * 64 + quad * 4;
#pragma unroll
    for (int db = 0; db < 4; ++db) {
      uint2 pk;
      pk.x = pack2(o[db][qb][0] * inv[qb], o[db][qb][1] * inv[qb]);
      pk.y = pack2(o[db][qb][2] * inv[qb], o[db][qb][3] * inv[qb]);
      *(uint2*)(xr + db * 16) = pk;
    }
  }
}

// ---------------- out GEMM: out = X @ Wout^T + bias, 64x128 tiles -------------------
// Same counted-vmcnt 3-buffer schedule (6 DMAs/tile/wave -> vmcnt(6)). LDS 72 KB ->
// 2 blocks/CU, grid 512 = 2/CU resident. Grid (x=64 mblk, y=8 obk): linear%8 = mblk%8
// -> all 8 obk sharers of an X slab on one XCD.
__global__ __launch_bounds__(256, 2) void out_gemm(const uint16_t* __restrict__ Xg,
                                                   const uint16_t* __restrict__ Wb,
                                                   const float* __restrict__ bias,
                                                   float* __restrict__ out) {
  __shared__ uint16_t Xt[3][64 * 64];
  __shared__ uint16_t Wt[3][128 * 64];
  const int t = threadIdx.x, w = t >> 6, lane = t & 63, quad = lane >> 4, l16 = lane & 15;
  const int m0 = blockIdx.x * 64, o0 = blockIdx.y * 128;
  const int srow = lane >> 3, sc8 = (lane & 7) ^ (lane >> 3);

  floatx4 acc[8];
#pragma unroll
  for (int j = 0; j < 8; ++j) acc[j] = floatx4{0.f, 0.f, 0.f, 0.f};

  auto stage = [&](int buf, int kt) {  // 6 DMA instrs/wave
#pragma unroll
    for (int i = 0; i < 2; ++i) {   // X: 16 rows/wave
      int r0 = w * 16 + i * 8;
      gl_lds16(Xg + (size_t)(m0 + r0 + srow) * 1024 + kt * 64 + sc8 * 8, &Xt[buf][r0 * 64]);
    }
#pragma unroll
    for (int i = 0; i < 4; ++i) {   // W: 32 rows/wave
      int r0 = w * 32 + i * 8;
      gl_lds16(Wb + (size_t)(o0 + r0 + srow) * 1024 + kt * 64 + sc8 * 8, &Wt[buf][r0 * 64]);
    }
  };

  stage(0, 0);
  stage(1, 1);

  int cur = 0;
  for (int kt = 0; kt < 16; ++kt) {
    if (kt + 1 < 16) asm volatile("s_waitcnt vmcnt(6)" ::: "memory");
    else             asm volatile("s_waitcnt vmcnt(0)" ::: "memory");
    __builtin_amdgcn_s_barrier();
    if (kt + 2 < 16) {
      int tgt = cur + 2; if (tgt >= 3) tgt -= 3;
      stage(tgt, kt + 2);
    }
#pragma unroll
    for (int kc = 0; kc < 2; ++kc) {
      int ra = w * 16 + l16;
      short8 a = *(const short8*)(&Xt[cur][ra * 64 + ((kc * 4 + quad) ^ (ra & 7)) * 8]);
#pragma unroll
      for (int nf = 0; nf < 8; ++nf) {
        int rb = nf * 16 + l16;
        short8 b = *(const short8*)(&Wt[cur][rb * 64 + ((kc * 4 + quad) ^ (rb & 7)) * 8]);
        acc[nf] = __builtin_amdgcn_mfma_f32_16x16x32_bf16(a, b, acc[nf], 0, 0, 0);
      }
    }
    asm volatile("s_waitcnt lgkmcnt(0)" ::: "memory");
    cur = (cur + 1 == 3) ? 0 : cur + 1;
  }

#pragma unroll
  for (int nf = 0; nf < 8; ++nf) {
    float bv = bias[o0 + nf * 16 + l16];
#pragma unroll
    for (int r = 0; r < 4; ++r)
      out[(size_t)(m0 + w * 16 + quad * 4 + r) * 1024 + o0 + nf * 16 + l16] = acc[nf][r] + bv;
  }
}

extern "C" void kernel_launch(void* const* d_in, const int* in_sizes, int n_in,
                              void* d_out, int out_size, void* d_ws, size_t ws_size,
                              hipStream_t stream) {
  const float* values = (const float*)d_in[0];
  const float* keys   = (const float*)d_in[1];
  const float* query  = (const float*)d_in[2];
  const float* Wv     = (const float*)d_in[3];
  const float* Wk     = (const float*)d_in[4];
  const float* Wq     = (const float*)d_in[5];
  const float* Wout   = (const float*)d_in[6];
  const float* bout   = (const float*)d_in[7];
  float* out = (float*)d_out;
  (void)ws_size;

  uint16_t* ws  = (uint16_t*)d_ws;
  uint16_t* qp  = ws;                                // 8 MB bf16 [nh][l][d]
  uint16_t* kp  = ws + (size_t)4194304;              // 8 MB bf16 [nh][l][d]
  uint16_t* vp  = ws + (size_t)8388608;              // 8 MB f16  [nh][d][l]
  uint16_t* wbf = ws + (size_t)12582912;             // 2 MB bf16 Wout
  uint16_t* xp  = ws + (size_t)13631488;             // 8 MB bf16 X = normalized attn out

  prep_kernel<<<dim3(1024), dim3(256), 0, stream>>>(values, keys, query, Wv, Wk, Wq, Wout,
                                                    qp, kp, vp, wbf);
  flash_kernel<<<dim3(32, 16), dim3(256), 0, stream>>>(qp, kp, vp, xp);
  out_gemm<<<dim3(64, 8), dim3(256), 0, stream>>>(xp, wbf, bout, out);
}

// Round 5
// 176.460 us; speedup vs baseline: 1.0349x; 1.0245x over previous
//
#include <hip/hip_runtime.h>
#include <cstdint>

typedef __attribute__((ext_vector_type(8))) short short8;      // 8 bf16 = 4 VGPRs
typedef __attribute__((ext_vector_type(4))) float floatx4;     // MFMA C/D frag
typedef __attribute__((ext_vector_type(4))) _Float16 half4;    // 16x16x16 f16 A/B frag

#define DEV __device__ __forceinline__

constexpr int NB = 2, Lseq = 2048, NH = 16, HD = 64, EMB = 1024;
// fold softmax scale (1/sqrt(1024)) and log2(e) into Wq so flash uses exp2
constexpr float QSCALE = 0.03125f * 1.4426950408889634f;

DEV uint16_t f2bf(float f) {  // round-to-nearest-even f32 -> bf16
  uint32_t x = __builtin_bit_cast(uint32_t, f);
  x += 0x7fffu + ((x >> 16) & 1u);
  return (uint16_t)(x >> 16);
}

// pack two f32 -> two bf16 in one dword (round-half-up via bias, then v_perm)
DEV uint32_t pack2(float lo, float hi) {
  uint32_t a = __builtin_bit_cast(uint32_t, lo) + 0x8000u;
  uint32_t b = __builtin_bit_cast(uint32_t, hi) + 0x8000u;
  return __builtin_amdgcn_perm(b, a, 0x07060302);
}

DEV uint32_t packh2(float lo, float hi) {  // two f32 -> packed f16 dword
  return __builtin_bit_cast(uint32_t, __builtin_amdgcn_cvt_pkrtz(lo, hi));
}

DEV void gl_lds16(const void* g, void* l) {  // async global->LDS, 16B/lane
  __builtin_amdgcn_global_load_lds((const __attribute__((address_space(1))) void*)g,
                                   (__attribute__((address_space(3))) void*)l, 16, 0, 0);
}

// load 8 consecutive f32, scale, convert to a bf16 MFMA frag chunk
DEV short8 ld8bf(const float* p, float sc) {
  float4 u = *(const float4*)p;
  float4 v = *(const float4*)(p + 4);
  union { short8 s; uint32_t d[4]; } r;
  r.d[0] = pack2(u.x * sc, u.y * sc);
  r.d[1] = pack2(u.z * sc, u.w * sc);
  r.d[2] = pack2(v.x * sc, v.y * sc);
  r.d[3] = pack2(v.z * sc, v.w * sc);
  return r.s;
}

// ---------------- prep: Q/K/V projections (MFMA, LDS-free) + Wout cvt ----------------
__global__ __launch_bounds__(256) void prep_kernel(
    const float* __restrict__ values, const float* __restrict__ keysrc,
    const float* __restrict__ query, const float* __restrict__ Wv,
    const float* __restrict__ Wk, const float* __restrict__ Wq,
    const float* __restrict__ Wout,
    uint16_t* __restrict__ qp, uint16_t* __restrict__ kp,
    uint16_t* __restrict__ vp, uint16_t* __restrict__ wbf) {
  const int t = threadIdx.x, w = t >> 6, lane = t & 63;
  const int quad = lane >> 4, l16 = lane & 15;
  const int wid = blockIdx.x * 4 + w;
  const int mat = wid >> 10, sub = wid & 1023;

  if (mat == 3) {  // Wout f32 -> bf16
#pragma unroll
    for (int i = 0; i < 4; ++i) {
      int idx = sub * 256 + i * 64 + lane;
      float4 v = ((const float4*)Wout)[idx];
      uint2 p;
      p.x = pack2(v.x, v.y);
      p.y = pack2(v.z, v.w);
      ((uint2*)wbf)[idx] = p;
    }
    return;
  }

  floatx4 c[4][4];
#pragma unroll
  for (int i = 0; i < 4; ++i)
#pragma unroll
    for (int j = 0; j < 4; ++j) c[i][j] = floatx4{0.f, 0.f, 0.f, 0.f};

  if (mat < 2) {
    // Q/K: A = W rows (m=e), B = x rows (n=r) -> D[e][r]; lane holds 4 consecutive e.
    const float* src = mat ? keysrc : query;
    const float* W   = mat ? Wk : Wq;
    const float asc  = mat ? 1.f : QSCALE;
    uint16_t* dst    = mat ? kp : qp;
    const int R0 = sub * 64;
    short8 a[4][2], b[4][2];
#pragma unroll
    for (int dc = 0; dc < 2; ++dc) {
#pragma unroll
      for (int f = 0; f < 4; ++f) {
        a[f][dc] = ld8bf(W + (size_t)(f * 16 + l16) * 64 + dc * 32 + quad * 8, asc);
        b[f][dc] = ld8bf(src + (size_t)(R0 + f * 16 + l16) * 64 + dc * 32 + quad * 8, 1.f);
      }
    }
#pragma unroll
    for (int dc = 0; dc < 2; ++dc)
#pragma unroll
      for (int mf = 0; mf < 4; ++mf)
#pragma unroll
        for (int nf = 0; nf < 4; ++nf)
          c[mf][nf] = __builtin_amdgcn_mfma_f32_16x16x32_bf16(a[mf][dc], b[nf][dc], c[mf][nf], 0, 0, 0);
#pragma unroll
    for (int nf = 0; nf < 4; ++nf) {
      int r = R0 + nf * 16 + l16;
      int h = r & 15, l = (r >> 4) & 2047, n = r >> 15;
      uint16_t* drow = dst + ((size_t)(n * 16 + h) * 2048 + l) * 64;
#pragma unroll
      for (int mf = 0; mf < 4; ++mf) {
        uint2 pk;
        pk.x = pack2(c[mf][nf][0], c[mf][nf][1]);
        pk.y = pack2(c[mf][nf][2], c[mf][nf][3]);
        *(uint2*)(drow + mf * 16 + quad * 4) = pk;
      }
    }
  } else {
    // V^T: A = x rows (m=l), B = Wv rows (n=d) -> D[l][d]; vp[nh][d][l] in f16.
    const int nh = sub >> 5, L0 = (sub & 31) * 64;
    const int n = nh >> 4, h = nh & 15;
    short8 a[4][2], b[4][2];
#pragma unroll
    for (int dc = 0; dc < 2; ++dc) {
#pragma unroll
      for (int f = 0; f < 4; ++f) {
        a[f][dc] = ld8bf(values + (size_t)(n * 2048 + L0 + f * 16 + l16) * 1024 + h * 64 + dc * 32 + quad * 8, 1.f);
        b[f][dc] = ld8bf(Wv + (size_t)(f * 16 + l16) * 64 + dc * 32 + quad * 8, 1.f);
      }
    }
#pragma unroll
    for (int dc = 0; dc < 2; ++dc)
#pragma unroll
      for (int mf = 0; mf < 4; ++mf)
#pragma unroll
        for (int nf = 0; nf < 4; ++nf)
          c[mf][nf] = __builtin_amdgcn_mfma_f32_16x16x32_bf16(a[mf][dc], b[nf][dc], c[mf][nf], 0, 0, 0);
#pragma unroll
    for (int nf = 0; nf < 4; ++nf) {
      int d = nf * 16 + l16;
      uint16_t* drow = vp + ((size_t)nh * 64 + d) * 2048 + L0;
#pragma unroll
      for (int mf = 0; mf < 4; ++mf) {
        uint2 pk;
        pk.x = packh2(c[mf][nf][0], c[mf][nf][1]);
        pk.y = packh2(c[mf][nf][2], c[mf][nf][3]);
        *(uint2*)(drow + mf * 16 + quad * 4) = pk;
      }
    }
  }
}

// ---------------- Flash attention: q-split, full key range, 4 blocks/CU -------------
// R0's proven schedule (2-buf LDS + __syncthreads, ones-MFMA l) at R0's proven
// occupancy (4 blocks/CU), but parallelism comes from splitting Q (64 rows/block,
// grid 32x32=1024) instead of K — so each block sees the FULL key range and can
// normalize + emit bf16 X in the epilogue (no f32 partial round-trip, no combine).
// Grid linear id % 8 = nh % 8 -> all 32 q-blocks of a head on one XCD; K+V per head
// = 512 KB, 4 heads/XCD fits L2.
__global__ __launch_bounds__(256, 4) void flash_kernel(const uint16_t* __restrict__ qp,
                                                       const uint16_t* __restrict__ kp,
                                                       const uint16_t* __restrict__ vp,
                                                       uint16_t* __restrict__ xg) {
  constexpr int kbn = 32;
  __shared__ uint16_t Kt[2][64 * 64];    // swizzled [key][d] bf16
  __shared__ uint16_t Vt[2][64 * 64];    // swizzled [d][key] f16
  const int t = threadIdx.x;
  const int w = t >> 6, lane = t & 63, quad = lane >> 4, l16 = lane & 15;
  const int nh = blockIdx.x, qt = blockIdx.y;
  const int q0 = qt * 64 + w * 16;       // 16 q-rows per wave
  const uint16_t* Qb = qp + (size_t)nh * Lseq * HD;
  const uint16_t* Kb = kp + (size_t)nh * Lseq * HD;
  const uint16_t* Vb = vp + (size_t)nh * HD * Lseq;
  const int srow = lane >> 3, sc8 = (lane & 7) ^ (lane >> 3);  // staging swizzle

  short8 bq[2];
  bq[0] = *(const short8*)(Qb + (q0 + l16) * 64 + quad * 8);
  bq[1] = *(const short8*)(Qb + (q0 + l16) * 64 + 32 + quad * 8);

  floatx4 o[4];      // O^T frags: row=d=db*16+quad*4+r, col=q=l16
  floatx4 lfr;       // ones^T P accumulator: every element = l_q for q=q0+l16
#pragma unroll
  for (int i = 0; i < 4; ++i) o[i] = floatx4{0.f, 0.f, 0.f, 0.f};
  lfr = floatx4{0.f, 0.f, 0.f, 0.f};
  const _Float16 one = (_Float16)1.0f;
  const half4 vone = {one, one, one, one};

#pragma unroll
  for (int i = 0; i < 2; ++i) {
    int r0 = w * 16 + i * 8;
    gl_lds16(Kb + (r0 + srow) * 64 + sc8 * 8, &Kt[0][r0 * 64]);
    gl_lds16(Vb + (size_t)(r0 + srow) * Lseq + sc8 * 8, &Vt[0][r0 * 64]);
  }

  for (int kb = 0; kb < kbn; ++kb) {
    __syncthreads();
    const int cur = kb & 1;
    if (kb + 1 < kbn) {
      const int nxt = cur ^ 1;
      const uint16_t* kg = Kb + (kb + 1) * (64 * 64);
#pragma unroll
      for (int i = 0; i < 2; ++i) {
        int r0 = w * 16 + i * 8;
        gl_lds16(kg + (r0 + srow) * 64 + sc8 * 8, &Kt[nxt][r0 * 64]);
        gl_lds16(Vb + (size_t)(r0 + srow) * Lseq + (kb + 1) * 64 + sc8 * 8, &Vt[nxt][r0 * 64]);
      }
    }

    // S^T = K Q^T
    floatx4 s[4];
#pragma unroll
    for (int kb16 = 0; kb16 < 4; ++kb16) s[kb16] = floatx4{0.f, 0.f, 0.f, 0.f};
#pragma unroll
    for (int dc = 0; dc < 2; ++dc) {
#pragma unroll
      for (int kb16 = 0; kb16 < 4; ++kb16) {
        int row = kb16 * 16 + l16;
        short8 ak = *(const short8*)(&Kt[cur][row * 64 + ((dc * 4 + quad) ^ (row & 7)) * 8]);
        s[kb16] = __builtin_amdgcn_mfma_f32_16x16x32_bf16(ak, bq[dc], s[kb16], 0, 0, 0);
      }
    }

    // p = exp2(s), packed in-register as 16x16x16 B-frags; l via ones-MFMA
    half4 bp[4];
#pragma unroll
    for (int kb16 = 0; kb16 < 4; ++kb16) {
      float p0 = __builtin_amdgcn_exp2f(s[kb16][0]);
      float p1 = __builtin_amdgcn_exp2f(s[kb16][1]);
      float p2 = __builtin_amdgcn_exp2f(s[kb16][2]);
      float p3 = __builtin_amdgcn_exp2f(s[kb16][3]);
      union { half4 h4; uint32_t d[2]; } u;
      u.d[0] = packh2(p0, p1);
      u.d[1] = packh2(p2, p3);
      bp[kb16] = u.h4;
    }
#pragma unroll
    for (int kb16 = 0; kb16 < 4; ++kb16)
      lfr = __builtin_amdgcn_mfma_f32_16x16x16f16(vone, bp[kb16], lfr, 0, 0, 0);

    // O^T += V^T P
#pragma unroll
    for (int kb16 = 0; kb16 < 4; ++kb16) {
#pragma unroll
      for (int db = 0; db < 4; ++db) {
        int row = db * 16 + l16;
        int ch = (kb16 * 2 + (quad >> 1)) ^ (row & 7);
        half4 av = *(const half4*)(&Vt[cur][row * 64 + ch * 8 + (quad & 1) * 4]);
        o[db] = __builtin_amdgcn_mfma_f32_16x16x16f16(av, bp[kb16], o[db], 0, 0, 0);
      }
    }
  }

  // epilogue: X[n*2048 + q][h*64 + d] = (O^T[d][q] / l_q) as bf16.
  // Lane holds d = db*16 + quad*4 + {0..3} for its fixed q = q0 + l16,
  // so each db is one aligned 8B uint2 store.
  const int nn = nh >> 4, h = nh & 15;
  const float inv = __builtin_amdgcn_rcpf(lfr[0]);
  uint16_t* xr = xg + ((size_t)(nn * 2048 + q0 + l16)) * 1024 + h * 64 + quad * 4;
#pragma unroll
  for (int db = 0; db < 4; ++db) {
    uint2 pk;
    pk.x = pack2(o[db][0] * inv, o[db][1] * inv);
    pk.y = pack2(o[db][2] * inv, o[db][3] * inv);
    *(uint2*)(xr + db * 16) = pk;
  }
}

// ---------------- out GEMM: out = X @ Wout^T + bias, 64x128 tiles -------------------
// Counted-vmcnt 3-buffer schedule (6 DMAs/tile/wave -> vmcnt(6)); this version
// measured ~6us better than the 2-buf syncthreads one in R2's "rest" delta.
// Grid (x=64 mblk, y=8 obk): linear%8 = mblk%8 -> all 8 obk sharers of an X slab on
// one XCD. LDS 72KB -> 2 blocks/CU, grid 512 = 2/CU resident.
__global__ __launch_bounds__(256, 2) void out_gemm(const uint16_t* __restrict__ Xg,
                                                   const uint16_t* __restrict__ Wb,
                                                   const float* __restrict__ bias,
                                                   float* __restrict__ out) {
  __shared__ uint16_t Xt[3][64 * 64];
  __shared__ uint16_t Wt[3][128 * 64];
  const int t = threadIdx.x, w = t >> 6, lane = t & 63, quad = lane >> 4, l16 = lane & 15;
  const int m0 = blockIdx.x * 64, o0 = blockIdx.y * 128;
  const int srow = lane >> 3, sc8 = (lane & 7) ^ (lane >> 3);

  floatx4 acc[8];
#pragma unroll
  for (int j = 0; j < 8; ++j) acc[j] = floatx4{0.f, 0.f, 0.f, 0.f};

  auto stage = [&](int buf, int kt) {  // 6 DMA instrs/wave
#pragma unroll
    for (int i = 0; i < 2; ++i) {   // X: 16 rows/wave
      int r0 = w * 16 + i * 8;
      gl_lds16(Xg + (size_t)(m0 + r0 + srow) * 1024 + kt * 64 + sc8 * 8, &Xt[buf][r0 * 64]);
    }
#pragma unroll
    for (int i = 0; i < 4; ++i) {   // W: 32 rows/wave
      int r0 = w * 32 + i * 8;
      gl_lds16(Wb + (size_t)(o0 + r0 + srow) * 1024 + kt * 64 + sc8 * 8, &Wt[buf][r0 * 64]);
    }
  };

  stage(0, 0);
  stage(1, 1);

  int cur = 0;
  for (int kt = 0; kt < 16; ++kt) {
    if (kt + 1 < 16) asm volatile("s_waitcnt vmcnt(6)" ::: "memory");
    else             asm volatile("s_waitcnt vmcnt(0)" ::: "memory");
    __builtin_amdgcn_s_barrier();
    if (kt + 2 < 16) {
      int tgt = cur + 2; if (tgt >= 3) tgt -= 3;
      stage(tgt, kt + 2);
    }
#pragma unroll
    for (int kc = 0; kc < 2; ++kc) {
      int ra = w * 16 + l16;
      short8 a = *(const short8*)(&Xt[cur][ra * 64 + ((kc * 4 + quad) ^ (ra & 7)) * 8]);
#pragma unroll
      for (int nf = 0; nf < 8; ++nf) {
        int rb = nf * 16 + l16;
        short8 b = *(const short8*)(&Wt[cur][rb * 64 + ((kc * 4 + quad) ^ (rb & 7)) * 8]);
        acc[nf] = __builtin_amdgcn_mfma_f32_16x16x32_bf16(a, b, acc[nf], 0, 0, 0);
      }
    }
    asm volatile("s_waitcnt lgkmcnt(0)" ::: "memory");
    cur = (cur + 1 == 3) ? 0 : cur + 1;
  }

#pragma unroll
  for (int nf = 0; nf < 8; ++nf) {
    float bv = bias[o0 + nf * 16 + l16];
#pragma unroll
    for (int r = 0; r < 4; ++r)
      out[(size_t)(m0 + w * 16 + quad * 4 + r) * 1024 + o0 + nf * 16 + l16] = acc[nf][r] + bv;
  }
}

extern "C" void kernel_launch(void* const* d_in, const int* in_sizes, int n_in,
                              void* d_out, int out_size, void* d_ws, size_t ws_size,
                              hipStream_t stream) {
  const float* values = (const float*)d_in[0];
  const float* keys   = (const float*)d_in[1];
  const float* query  = (const float*)d_in[2];
  const float* Wv     = (const float*)d_in[3];
  const float* Wk     = (const float*)d_in[4];
  const float* Wq     = (const float*)d_in[5];
  const float* Wout   = (const float*)d_in[6];
  const float* bout   = (const float*)d_in[7];
  float* out = (float*)d_out;
  (void)ws_size;

  uint16_t* ws  = (uint16_t*)d_ws;
  uint16_t* qp  = ws;                                // 8 MB bf16 [nh][l][d]
  uint16_t* kp  = ws + (size_t)4194304;              // 8 MB bf16 [nh][l][d]
  uint16_t* vp  = ws + (size_t)8388608;              // 8 MB f16  [nh][d][l]
  uint16_t* wbf = ws + (size_t)12582912;             // 2 MB bf16 Wout
  uint16_t* xp  = ws + (size_t)13631488;             // 8 MB bf16 X = normalized attn out

  prep_kernel<<<dim3(1024), dim3(256), 0, stream>>>(values, keys, query, Wv, Wk, Wq, Wout,
                                                    qp, kp, vp, wbf);
  flash_kernel<<<dim3(32, 32), dim3(256), 0, stream>>>(qp, kp, vp, xp);
  out_gemm<<<dim3(64, 8), dim3(256), 0, stream>>>(xp, wbf, bout, out);
}